// Round 8
// baseline (114.956 us; speedup 1.0000x reference)
//
#include <hip/hip_runtime.h>

// ---------------------------------------------------------------------------
// Attention fused for MI355X (gfx950)
//   x:[4,4096,1024] f32, Wq/Wk/Wv:[128,1024] f32 -> out:[4,4096,128] f32
// Round 8: round-7 structure, but P-transpose + cross-half reduces reverted
//          to the round-6-proven __shfl_xor(.,32) form (permlane32_swap's
//          half-convention was the prime correctness suspect).
//          qkv = BM=32 grid 512 (2 blocks/CU), W 3-buf staged 2 ahead,
//          counted vmcnt(7); attn = 48KB (K dbuf + V single), counted
//          vmcnt(4) barriers, CHUNK=8 uniform items + XCD swizzle.
// ws: [0,4M) q bf16 (scaled by log2e/sqrt(128)), [4M,8M) k bf16,
//     [8M,12M) v^T bf16 [B][128][T], [12M,12.75M) W bf16,
//     [13M,49M) o partials f32 [576][128][128], [50M,50.6M) m,l partials.
// ---------------------------------------------------------------------------

typedef __attribute__((ext_vector_type(8))) short short8;
typedef __attribute__((ext_vector_type(8))) unsigned short ushort8;
typedef __attribute__((ext_vector_type(4))) unsigned short ushort4v;
typedef __attribute__((ext_vector_type(4))) float f32x4;
typedef __attribute__((ext_vector_type(16))) float f32x16;
typedef __attribute__((ext_vector_type(4))) int int4v;
typedef __attribute__((ext_vector_type(2))) unsigned int u32x2;
typedef unsigned int u32;
typedef unsigned short u16;

#define MFMA32(a, b, c) __builtin_amdgcn_mfma_f32_32x32x16_bf16((a), (b), (c), 0, 0, 0)
#define WAITVM(n) asm volatile("s_waitcnt vmcnt(" #n ")" ::: "memory")
#define WAITLGKM0() asm volatile("s_waitcnt lgkmcnt(0)" ::: "memory")
#define SCHEDB() __builtin_amdgcn_sched_barrier(0)
#define NEG_INF (-1e30f)

#define CHUNK 8             // kv-steps per work item
#define PITEMS 144          // items per batch = sum_{qt<32} ceil((2qt+2)/8)
#define NITEMS 576          // 4 * PITEMS  (= 8 * 72, XCD-swizzle exact)

__device__ __forceinline__ void gload16(const void* g, void* l) {
  __builtin_amdgcn_global_load_lds((const __attribute__((address_space(1))) u32*)g,
                                   (__attribute__((address_space(3))) u32*)l, 16, 0, 0);
}

__device__ __forceinline__ u16 f2bf(float f) {  // f32 -> bf16 bits, RNE
  u32 u = __builtin_bit_cast(u32, f);
  u = u + 0x7FFFu + ((u >> 16) & 1u);
  return (u16)(u >> 16);
}

__device__ __forceinline__ u32 cvtpk(float lo, float hi) {  // {bf16(lo),bf16(hi)}
  u32 r;
  asm("v_cvt_pk_bf16_f32 %0, %1, %2" : "=v"(r) : "v"(lo), "v"(hi));
  return r;
}

// ---------------- kernel 0: W f32 -> bf16 (Wb[384][1024]) -------------------
__global__ __launch_bounds__(256) void wconv_kernel(const float* __restrict__ Wq,
                                                    const float* __restrict__ Wk,
                                                    const float* __restrict__ Wv,
                                                    u16* __restrict__ Wb) {
  int g = (blockIdx.x * 256 + threadIdx.x) * 8;
  const float* src;
  if (g < 131072)      src = Wq + g;
  else if (g < 262144) src = Wk + (g - 131072);
  else                 src = Wv + (g - 262144);
  float4 a = *(const float4*)src;
  float4 b = *(const float4*)(src + 4);
  ushort8 o;
  o[0] = f2bf(a.x); o[1] = f2bf(a.y); o[2] = f2bf(a.z); o[3] = f2bf(a.w);
  o[4] = f2bf(b.x); o[5] = f2bf(b.y); o[6] = f2bf(b.z); o[7] = f2bf(b.w);
  *(ushort8*)(Wb + g) = o;
}

// ---------------- kernel 1: fused QKV projection ----------------------------
// BM=32, BK=32, grid 512 (2 blocks/CU), 256 thr = 4 waves (wave w: n-tiles
// 3w..3w+2). W [384][32] 3-buffered, staged 2 steps ahead, counted vmcnt(7);
// X [32][32] reg-staged dbuf. One raw barrier per step. Coalesced epilogue.
#define QK_SCALE 0.127517446f  // (1/sqrt(128)) * log2(e)

__global__ __launch_bounds__(256, 2) void qkv_proj_kernel(const float* __restrict__ x,
                                                          const u16* __restrict__ Wb,
                                                          u16* __restrict__ qout,
                                                          u16* __restrict__ kout,
                                                          u16* __restrict__ vtout) {
  __shared__ __align__(16) unsigned char Wlds[3][24576];  // [384][32] bf16 swz
  __shared__ __align__(16) unsigned char Xlds[2][2048];   // [32][32] bf16 swz
  const int tid = threadIdx.x;
  const int w = tid >> 6;
  const int l = tid & 63;
  const int h = l >> 5, n32 = l & 31;
  const int m0 = (int)blockIdx.x * 32;

  // x staging: thread -> (row xr, 4-f32 group xc); coalesced 128B per 8 thr
  const int xr = tid >> 3, xc = tid & 7;
  const float* xsrc = x + (size_t)(m0 + xr) * 1024 + xc * 4;
  const int xbyte = ((((xc >> 1) ^ (xr & 3)) << 4) | ((xc & 1) << 3));

  f32x16 acc[3];
#pragma unroll
  for (int j = 0; j < 3; ++j)
#pragma unroll
    for (int r = 0; r < 16; ++r) acc[j][r] = 0.f;

  // stage W k-slice ks (384 rows x 64B): 1536 chunks / 256 thr = 6 each
#define STAGE_W(buf, ks)                                                       \
  {                                                                            \
    _Pragma("unroll") for (int c = 0; c < 6; ++c) {                            \
      int L = c * 256 + tid;                                                   \
      int row = L >> 2, chp = L & 3;                                           \
      int gch = chp ^ (row & 3);                                               \
      gload16((const char*)Wb + row * 2048 + (ks) * 64 + gch * 16,             \
              (unsigned char*)Wlds[buf] + c * 4096 + w * 1024);                \
    }                                                                          \
  }
#define WRITE_X(buf, v4)                                                       \
  {                                                                            \
    u32x2 p;                                                                   \
    p[0] = cvtpk((v4).x, (v4).y);                                              \
    p[1] = cvtpk((v4).z, (v4).w);                                              \
    *(u32x2*)((unsigned char*)Xlds[buf] + xr * 64 + xbyte) = p;                \
  }

  // prologue: x(0),W(0),x(1),W(1) in flight; X(0) written
  float4 xa = *(const float4*)(xsrc);          // x(0)
  STAGE_W(0, 0);
  float4 xb = *(const float4*)(xsrc + 32);     // x(1)
  STAGE_W(1, 1);
  WRITE_X(0, xa);                              // compiler waits x(0) only

  for (int s = 0; s < 32; ++s) {
    if (s < 31) { WAITVM(7); } else { WAITVM(0); }  // W(s) landed (own)
    WAITLGKM0();                    // X writes retired
    __builtin_amdgcn_s_barrier();   // W(s), X(s) visible to all waves
    SCHEDB();
    if (s < 31) WRITE_X((s + 1) & 1, xb);  // compiler waits x(s+1)
    if (s < 30) {
      xb = *(const float4*)(xsrc + (s + 2) * 32);
      STAGE_W((s + 2) % 3, s + 2);
    }
    SCHEDB();
    const char* xb0 = (const char*)Xlds[s & 1];
    const char* wb0 = (const char*)Wlds[s % 3];
    __builtin_amdgcn_s_setprio(1);
#pragma unroll
    for (int k16 = 0; k16 < 2; ++k16) {
      short8 a = *(const short8*)(xb0 + n32 * 64 +
                                  ((k16 * 32 + h * 16) ^ ((n32 & 3) << 4)));
#pragma unroll
      for (int j = 0; j < 3; ++j) {
        int nrow = (w * 3 + j) * 32 + n32;
        short8 b = *(const short8*)(wb0 + nrow * 64 +
                                    ((k16 * 32 + h * 16) ^ ((nrow & 3) << 4)));
        acc[j] = MFMA32(a, b, acc[j]);
      }
    }
    __builtin_amdgcn_s_setprio(0);
  }
#undef STAGE_W
#undef WRITE_X

  // ---- epilogue. C layout: col=lane&31, row=(r&3)+8*(r>>2)+4h ----
  // q,k (tiles 0..7) through LDS for coalesced stores; v (8..11) direct.
  __syncthreads();  // compute done; safe to clobber Wlds
  u16* cl = (u16*)&Wlds[0][0];  // [32 m][256 n] bf16 = 16 KB
#pragma unroll
  for (int j = 0; j < 3; ++j) {
    int ti = w * 3 + j;
    if (ti < 8) {
      float sc = (ti < 4) ? QK_SCALE : 1.0f;
#pragma unroll
      for (int r = 0; r < 16; ++r) {
        int mm = (r & 3) + 8 * (r >> 2) + 4 * h;
        cl[mm * 256 + ti * 32 + n32] = f2bf(acc[j][r] * sc);
      }
    } else {
      int d = (ti - 8) * 32 + n32;
#pragma unroll
      for (int rq = 0; rq < 4; ++rq) {
        int t0 = m0 + rq * 8 + 4 * h;
        ushort4v o4;
#pragma unroll
        for (int i = 0; i < 4; ++i) o4[i] = f2bf(acc[j][rq * 4 + i]);
        *(ushort4v*)&vtout[(size_t)((t0 >> 12) * 128 + d) * 4096 + (t0 & 4095)] = o4;
      }
    }
  }
  __syncthreads();
  {
    int row = tid >> 3;               // 0..31
    int col0 = (tid & 7) * 32;        // 0..224
#pragma unroll
    for (int c = 0; c < 4; ++c) {
      int col = col0 + c * 8;
      ushort8 v8 = *(const ushort8*)(cl + row * 256 + col);
      if (col < 128) *(ushort8*)&qout[(size_t)(m0 + row) * 128 + col] = v8;
      else           *(ushort8*)&kout[(size_t)(m0 + row) * 128 + (col - 128)] = v8;
    }
  }
}

// ---------------- kernel 2: causal flash attention --------------------------
// Uniform items (CHUNK=8 kv-steps), XCD-swizzled. 256 thr = 4 waves x 32 q.
// K dbuf + V single (48 KB -> 3 blocks/CU); counted-wait barriers.
// P-transpose and cross-half reduces via __shfl_xor(.,32)  [round-6 proven].
template <bool SPLIT>
__global__ __launch_bounds__(256, 3) void attn_kernel(const u16* __restrict__ qws,
                                                      const u16* __restrict__ kws,
                                                      const u16* __restrict__ vtws,
                                                      float* __restrict__ out,
                                                      float* __restrict__ opart,
                                                      float* __restrict__ mlpart) {
  __shared__ __align__(16) unsigned char Klds[2][16384];  // [64 kv][128 d] swz
  __shared__ __align__(16) unsigned char Vlds[16384];     // [128 d][64 kv] swz

  const int tid = threadIdx.x;
  const int w = tid >> 6;
  const int l = tid & 63;
  const int h = l >> 5, q32 = l & 31;

  int bi, qt, s_lo, s_hi, item;
  if constexpr (SPLIT) {
    int bx = (int)blockIdx.x;
    item = (bx & 7) * 72 + (bx >> 3);       // bijective: XCD gets contig items
    bi = item / PITEMS;
    int r = item - bi * PITEMS;
    int base = 0;
    qt = 0;
    while (true) {                          // <=32 trivial iterations
      int cnt = (qt + 4) >> 2;              // chunks for tile qt
      if (r < base + cnt) break;
      base += cnt;
      ++qt;
    }
    int cc = r - base;
    int nsteps = 2 * qt + 2;
    s_lo = cc * CHUNK;
    s_hi = (s_lo + CHUNK < nsteps) ? s_lo + CHUNK : nsteps;
  } else {
    item = 0;
    int tb = (int)blockIdx.x;
    bi = tb & 3;
    qt = 31 - (tb >> 2);
    s_lo = 0;
    s_hi = 2 * qt + 2;
  }

  const int q0w = qt * 128 + w * 32;
  const int qg = q0w + q32;
  const int grow = bi * 4096 + qg;          // this lane's global q row
  const int ql = w * 32 + q32;              // row within the 128-row tile

  // Q B-frags resident: col=q32, k = ks*16 + 8h + e
  short8 qf[8];
  const u16* qp = qws + (size_t)grow * 128 + h * 8;
#pragma unroll
  for (int ks = 0; ks < 8; ++ks) qf[ks] = *(const short8*)(qp + ks * 16);

  f32x16 ot[4];
#pragma unroll
  for (int dt = 0; dt < 4; ++dt)
#pragma unroll
    for (int r = 0; r < 16; ++r) ot[dt][r] = 0.f;
  float mreg = NEG_INF, lsum = 0.f;

  const char* kbatch = (const char*)kws + (size_t)bi * 4096 * 256;
  const char* vbatch = (const char*)vtws + (size_t)bi * 128 * 8192;

#define STAGE_K(buf, kv0)                                                      \
  {                                                                            \
    _Pragma("unroll") for (int c = 0; c < 4; ++c) {                            \
      int L = c * 256 + tid;                                                   \
      int row = L >> 4, chp = L & 15;                                          \
      int gch = chp ^ (row & 7);                                               \
      gload16(kbatch + (size_t)((kv0) + row) * 256 + gch * 16,                 \
              (unsigned char*)Klds[buf] + c * 4096 + w * 1024);                \
    }                                                                          \
  }
#define STAGE_V(kv0)                                                           \
  {                                                                            \
    _Pragma("unroll") for (int c = 0; c < 4; ++c) {                            \
      int L = c * 256 + tid;                                                   \
      int row = L >> 3, chp = L & 7;                                           \
      int gch = chp ^ (row & 7);                                               \
      gload16(vbatch + (size_t)row * 8192 + (size_t)(kv0) * 2 + gch * 16,      \
              (unsigned char*)Vlds + c * 4096 + w * 1024);                     \
    }                                                                          \
  }

  STAGE_K(0, s_lo * 64);   // 4 vm
  SCHEDB();
  STAGE_V(s_lo * 64);      // 4 vm   -> invariant at entry: [K(s)4, V(s)4]
  SCHEDB();
  int cur = 0;

  for (int s = s_lo; s < s_hi; ++s) {
    const bool more = (s + 1 < s_hi);
    WAITVM(4);                       // K(s) landed (own); V(s) in flight
    __builtin_amdgcn_s_barrier();    // B1: K(s) visible; prev iter fully done
    SCHEDB();
    if (more) STAGE_K(cur ^ 1, (s + 1) * 64);  // +4
    SCHEDB();
    const int kv0 = s * 64;
    const bool active = (kv0 <= q0w + 31);     // wave-uniform

    f32x16 st0, st1;
    if (active) {
      // ---- S^T = K · Q^T ----
#pragma unroll
      for (int r = 0; r < 16; ++r) { st0[r] = 0.f; st1[r] = 0.f; }
      const char* Kb = (const char*)Klds[cur];
      const int sw = (q32 & 7) << 4;
      __builtin_amdgcn_s_setprio(1);
#pragma unroll
      for (int ks = 0; ks < 8; ++ks) {
        int coff = ks * 32 + h * 16;
        short8 a0 = *(const short8*)(Kb + q32 * 256 + (coff ^ sw));
        st0 = MFMA32(a0, qf[ks], st0);
        short8 a1 = *(const short8*)(Kb + (32 + q32) * 256 + (coff ^ sw));
        st1 = MFMA32(a1, qf[ks], st1);
      }
      __builtin_amdgcn_s_setprio(0);

      // ---- causal mask ----
      if (kv0 + 63 > q0w) {
#pragma unroll
        for (int r = 0; r < 16; ++r) {
          int kvr = kv0 + (r & 3) + 8 * (r >> 2) + 4 * h;
          if (kvr > qg) st0[r] = NEG_INF;
          if (kvr + 32 > qg) st1[r] = NEG_INF;
        }
      }

      // ---- online softmax (exp2 domain), defer-max THR=8 ----
      float tmax = st0[0];
#pragma unroll
      for (int r = 1; r < 16; ++r) tmax = fmaxf(tmax, st0[r]);
#pragma unroll
      for (int r = 0; r < 16; ++r) tmax = fmaxf(tmax, st1[r]);
      tmax = fmaxf(tmax, __shfl_xor(tmax, 32));
      if (!__all(tmax <= mreg + 8.0f)) {
        float mnew = fmaxf(mreg, tmax);
        float alpha = exp2f(mreg - mnew);
        lsum *= alpha;
#pragma unroll
        for (int dt = 0; dt < 4; ++dt)
#pragma unroll
          for (int r = 0; r < 16; ++r) ot[dt][r] *= alpha;
        mreg = mnew;
      }
      float rs = 0.f;
#pragma unroll
      for (int r = 0; r < 16; ++r) { st0[r] = exp2f(st0[r] - mreg); rs += st0[r]; }
#pragma unroll
      for (int r = 0; r < 16; ++r) { st1[r] = exp2f(st1[r] - mreg); rs += st1[r]; }
      rs += __shfl_xor(rs, 32);
      lsum += rs;
    }

    if (more) { WAITVM(4); } else { WAITVM(0); }  // V(s) landed (own)
    __builtin_amdgcn_s_barrier();                 // Bv: V(s) visible
    SCHEDB();

    if (active) {
      // ---- O^T += V^T · P^T : P B-frags via cvt_pk + shfl_xor (r6 proven) --
      const char* Vb = (const char*)Vlds;
      const int sw = (q32 & 7) << 4;
      __builtin_amdgcn_s_setprio(1);
#pragma unroll
      for (int t = 0; t < 4; ++t) {
        const f32x16& stt = (t < 2) ? st0 : st1;
        const int rb = (t & 1) * 8;
        u32 A0 = cvtpk(stt[rb + 0], stt[rb + 1]);
        u32 C0 = cvtpk(stt[rb + 2], stt[rb + 3]);
        u32 B0 = cvtpk(stt[rb + 4], stt[rb + 5]);
        u32 D0 = cvtpk(stt[rb + 6], stt[rb + 7]);
        u32 Ax = (u32)__shfl_xor((int)A0, 32);
        u32 Bx = (u32)__shfl_xor((int)B0, 32);
        u32 Cx = (u32)__shfl_xor((int)C0, 32);
        u32 Dx = (u32)__shfl_xor((int)D0, 32);
        int4v pbv;
        pbv[0] = (int)(h ? Bx : A0);
        pbv[1] = (int)(h ? Dx : C0);
        pbv[2] = (int)(h ? B0 : Ax);
        pbv[3] = (int)(h ? D0 : Cx);
        short8 pb = __builtin_bit_cast(short8, pbv);
#pragma unroll
        for (int dt = 0; dt < 4; ++dt) {
          int row = dt * 32 + q32;
          short8 va = *(const short8*)(Vb + row * 128 + ((t * 32 + h * 16) ^ sw));
          ot[dt] = MFMA32(va, pb, ot[dt]);
        }
      }
      __builtin_amdgcn_s_setprio(0);
    }

    if (more) {
      __builtin_amdgcn_s_barrier();   // B2: all waves done reading V(s)
      SCHEDB();
      STAGE_V((s + 1) * 64);          // +4 -> invariant restored
      SCHEDB();
    }
    cur ^= 1;
  }

  if constexpr (!SPLIT) {
    float inv = 1.0f / lsum;
    float* ob = out + (size_t)grow * 128;
#pragma unroll
    for (int dt = 0; dt < 4; ++dt)
#pragma unroll
      for (int rq = 0; rq < 4; ++rq) {
        f32x4 v4;
#pragma unroll
        for (int i = 0; i < 4; ++i) v4[i] = ot[dt][rq * 4 + i] * inv;
        *(f32x4*)(ob + dt * 32 + rq * 8 + 4 * h) = v4;
      }
  } else {
    float* ob = opart + (size_t)item * 16384 + (size_t)ql * 128;
#pragma unroll
    for (int dt = 0; dt < 4; ++dt)
#pragma unroll
      for (int rq = 0; rq < 4; ++rq) {
        f32x4 v4;
#pragma unroll
        for (int i = 0; i < 4; ++i) v4[i] = ot[dt][rq * 4 + i];
        *(f32x4*)(ob + dt * 32 + rq * 8 + 4 * h) = v4;
      }
    if (h == 0) {
      mlpart[item * 128 + ql] = mreg;
      mlpart[NITEMS * 128 + item * 128 + ql] = lsum;
    }
  }
#undef STAGE_K
#undef STAGE_V
}

// ---------------- kernel 3: variable-split combine --------------------------
__global__ __launch_bounds__(256) void combine_kernel(const float* __restrict__ opart,
                                                      const float* __restrict__ mlpart,
                                                      float* __restrict__ out) {
  int idx = blockIdx.x * 256 + threadIdx.x;  // 16384*128 threads
  int row = idx >> 7, d = idx & 127;
  int bi = row >> 12, lrow = row & 4095;
  int qt = lrow >> 7, ql = lrow & 127;
  int base = 0;
#pragma unroll 1
  for (int j = 0; j < qt; ++j) base += (j + 4) >> 2;
  int nspl = (qt + 4) >> 2;
  int it0 = bi * PITEMS + base;

  float M = NEG_INF;
#pragma unroll 1
  for (int j = 0; j < nspl; ++j)
    M = fmaxf(M, mlpart[(it0 + j) * 128 + ql]);
  float L = 0.f, O = 0.f;
#pragma unroll 1
  for (int j = 0; j < nspl; ++j) {
    float s = exp2f(mlpart[(it0 + j) * 128 + ql] - M);
    L += mlpart[NITEMS * 128 + (it0 + j) * 128 + ql] * s;
    O += opart[(size_t)(it0 + j) * 16384 + (size_t)ql * 128 + d] * s;
  }
  out[(size_t)row * 128 + d] = O / L;
}

// ---------------------------------------------------------------------------
extern "C" void kernel_launch(void* const* d_in, const int* in_sizes, int n_in,
                              void* d_out, int out_size, void* d_ws, size_t ws_size,
                              hipStream_t stream) {
  (void)in_sizes; (void)n_in; (void)out_size;
  const float* x  = (const float*)d_in[0];
  const float* Wq = (const float*)d_in[1];
  const float* Wk = (const float*)d_in[2];
  const float* Wv = (const float*)d_in[3];
  float* out = (float*)d_out;
  char* ws = (char*)d_ws;
  u16* qws  = (u16*)(ws);
  u16* kws  = (u16*)(ws + (4u << 20));
  u16* vtws = (u16*)(ws + (8u << 20));
  u16* Wb   = (u16*)(ws + (12u << 20));
  float* opart  = (float*)(ws + (13u << 20));   // 576*64KB = 36 MiB
  float* mlpart = (float*)(ws + (50u << 20));   // 2*576*128*4B = 576 KiB

  wconv_kernel<<<dim3(192), dim3(256), 0, stream>>>(Wq, Wk, Wv, Wb);
  qkv_proj_kernel<<<dim3(512), dim3(256), 0, stream>>>(x, Wb, qws, kws, vtws);
  if (ws_size >= ((size_t)52 << 20)) {
    attn_kernel<true><<<dim3(NITEMS), dim3(256), 0, stream>>>(qws, kws, vtws, nullptr, opart, mlpart);
    combine_kernel<<<dim3(8192), dim3(256), 0, stream>>>(opart, mlpart, out);
  } else {
    attn_kernel<false><<<dim3(128), dim3(256), 0, stream>>>(qws, kws, vtws, out, nullptr, nullptr);
  }
}

// Round 9
// 91.021 us; speedup vs baseline: 1.2630x; 1.2630x over previous
//
#include <hip/hip_runtime.h>

// ---------------------------------------------------------------------------
// Attention fused for MI355X (gfx950)
//   x:[4,4096,1024] f32, Wq/Wk/Wv:[128,1024] f32 -> out:[4,4096,128] f32
// Round 9: attn/wconv/combine = round-6 verbatim (best measured: attn 40.4us).
//          qkv = round-6 internals (128B LDS rows, 1 sync/step) + N-SPLIT-2:
//          BM=64, N=192 per block -> grid 512 = 2 blocks/CU (64KB LDS).
//          ns = bx>>8 so the ns=1 pass re-reads x from L3.
// ws: [0,4M) q bf16 (scaled by log2e/sqrt(128)), [4M,8M) k bf16,
//     [8M,12M) v^T bf16 [B][128][T], [12M,12.75M) W bf16,
//     [13M,~44.2M) o partials f32 [476][128][128],
//     [47M,~47.5M) m,l partials f32 [2][476][128].
// ---------------------------------------------------------------------------

typedef __attribute__((ext_vector_type(8))) short short8;
typedef __attribute__((ext_vector_type(8))) unsigned short ushort8;
typedef __attribute__((ext_vector_type(4))) unsigned short ushort4v;
typedef __attribute__((ext_vector_type(4))) float f32x4;
typedef __attribute__((ext_vector_type(16))) float f32x16;
typedef __attribute__((ext_vector_type(4))) int int4v;
typedef __attribute__((ext_vector_type(2))) unsigned int u32x2;
typedef unsigned int u32;
typedef unsigned short u16;

#define MFMA32(a, b, c) __builtin_amdgcn_mfma_f32_32x32x16_bf16((a), (b), (c), 0, 0, 0)
#define WAITVM0() asm volatile("s_waitcnt vmcnt(0)" ::: "memory")
#define NEG_INF (-1e30f)

#define CHUNK 10            // kv-steps per work item
#define PITEMS 119          // items per batch  = sum_{qt<32} ceil((qt+1)/5)
#define NITEMS 476          // 4 * PITEMS

__device__ __forceinline__ void gload16(const void* g, void* l) {
  __builtin_amdgcn_global_load_lds((const __attribute__((address_space(1))) u32*)g,
                                   (__attribute__((address_space(3))) u32*)l, 16, 0, 0);
}

__device__ __forceinline__ u16 f2bf(float f) {  // f32 -> bf16 bits, RNE
  u32 u = __builtin_bit_cast(u32, f);
  u = u + 0x7FFFu + ((u >> 16) & 1u);
  return (u16)(u >> 16);
}

__device__ __forceinline__ u32 cvtpk(float lo, float hi) {  // {bf16(lo),bf16(hi)}
  u32 r;
  asm("v_cvt_pk_bf16_f32 %0, %1, %2" : "=v"(r) : "v"(lo), "v"(hi));
  return r;
}

// ---------------- kernel 0: W f32 -> bf16 (Wb[384][1024]) -------------------
__global__ __launch_bounds__(256) void wconv_kernel(const float* __restrict__ Wq,
                                                    const float* __restrict__ Wk,
                                                    const float* __restrict__ Wv,
                                                    u16* __restrict__ Wb) {
  int g = (blockIdx.x * 256 + threadIdx.x) * 8;
  const float* src;
  if (g < 131072)      src = Wq + g;
  else if (g < 262144) src = Wk + (g - 131072);
  else                 src = Wv + (g - 262144);
  float4 a = *(const float4*)src;
  float4 b = *(const float4*)(src + 4);
  ushort8 o;
  o[0] = f2bf(a.x); o[1] = f2bf(a.y); o[2] = f2bf(a.z); o[3] = f2bf(a.w);
  o[4] = f2bf(b.x); o[5] = f2bf(b.y); o[6] = f2bf(b.z); o[7] = f2bf(b.w);
  *(ushort8*)(Wb + g) = o;
}

// ---------------- kernel 1: fused QKV projection (N-split-2) ----------------
// grid 512: ns = bx>>8, m0 = (bx&255)*64. 256 thr = 4 waves: mh=w>>1 (32-row
// half), ng=w&1 (3 n-tiles of the 6 in this split). BK=64, 16 steps.
// W slice [192][64] bf16 dbuf (gload16, 128B rows, (row&7) swizzle);
// X [64][64] reg-staged (4xfloat4 -> cvt_pk -> 2x ds_write_b128) dbuf.
// One __syncthreads per step; prefetch issued post-barrier (1 step slack).
#define QK_SCALE 0.127517446f  // (1/sqrt(128)) * log2(e)

__global__ __launch_bounds__(256, 2) void qkv_proj_kernel(const float* __restrict__ x,
                                                          const u16* __restrict__ Wb,
                                                          u16* __restrict__ qout,
                                                          u16* __restrict__ kout,
                                                          u16* __restrict__ vtout) {
  __shared__ __align__(16) unsigned char Wlds[2][24576];  // [192][64] bf16 swz
  __shared__ __align__(16) unsigned char Xlds[2][8192];   // [64][64] bf16 swz
  const int tid = threadIdx.x;
  const int w = tid >> 6;
  const int l = tid & 63;
  const int h = l >> 5, n32 = l & 31;
  const int mh = w >> 1, ng = w & 1;
  const int bx = (int)blockIdx.x;
  const int ns = bx >> 8;               // 0: q+k[0:64), 1: k[64:128)+v
  const int m0 = (bx & 255) * 64;

  // x staging: thread -> row xr (0..63), 16 consecutive f32 at col xc*16
  const int xr = tid >> 2, xc = tid & 3;
  const float* xsrc = x + (size_t)(m0 + xr) * 1024 + xc * 16;
  const int xsw = (xr & 7) << 4;
  unsigned char* const xw[2] = {
    (unsigned char*)Xlds[0] + xr * 128,
    (unsigned char*)Xlds[1] + xr * 128};

  f32x16 acc[3];
#pragma unroll
  for (int j = 0; j < 3; ++j)
#pragma unroll
    for (int r = 0; r < 16; ++r) acc[j][r] = 0.f;

  // stage W slice k-step ks: 192 rows x 128B = 1536 chunks / 256 thr = 6 each
#define STAGE_W(buf, ks)                                                       \
  {                                                                            \
    _Pragma("unroll") for (int c = 0; c < 6; ++c) {                            \
      int L = c * 256 + tid;                                                   \
      int row = L >> 3, chp = L & 7;                                           \
      int gch = chp ^ (row & 7);                                               \
      gload16((const char*)Wb + (size_t)(ns * 192 + row) * 2048 + (ks) * 128 + \
                  gch * 16,                                                    \
              (unsigned char*)Wlds[buf] + c * 4096 + w * 1024);                \
    }                                                                          \
  }
#define WRITE_X(buf)                                                           \
  {                                                                            \
    int4v p0, p1;                                                              \
    p0[0] = (int)cvtpk(xa0.x, xa0.y); p0[1] = (int)cvtpk(xa0.z, xa0.w);        \
    p0[2] = (int)cvtpk(xa1.x, xa1.y); p0[3] = (int)cvtpk(xa1.z, xa1.w);        \
    p1[0] = (int)cvtpk(xa2.x, xa2.y); p1[1] = (int)cvtpk(xa2.z, xa2.w);        \
    p1[2] = (int)cvtpk(xa3.x, xa3.y); p1[3] = (int)cvtpk(xa3.z, xa3.w);        \
    *(int4v*)(xw[buf] + ((xc * 32) ^ xsw)) = p0;                               \
    *(int4v*)(xw[buf] + ((xc * 32 + 16) ^ xsw)) = p1;                          \
  }

  // prologue: x(0) in regs + W(0) in flight
  float4 xa0 = *(const float4*)(xsrc);
  float4 xa1 = *(const float4*)(xsrc + 4);
  float4 xa2 = *(const float4*)(xsrc + 8);
  float4 xa3 = *(const float4*)(xsrc + 12);
  STAGE_W(0, 0);

  const int am = mh * 32 + n32;         // this lane's A row in the 64-tile
  const int asw = (am & 7) << 4;
  int cur = 0;

  for (int ks = 0; ks < 16; ++ks) {
    WRITE_X(cur);     // compiler waits the x loads right here
    __syncthreads();  // vmcnt(0): W(ks) landed; lgkmcnt(0): X writes retired
    if (ks < 15) {    // prefetch x(ks+1) + W(ks+1) -> land during compute
      xa0 = *(const float4*)(xsrc + (ks + 1) * 64);
      xa1 = *(const float4*)(xsrc + (ks + 1) * 64 + 4);
      xa2 = *(const float4*)(xsrc + (ks + 1) * 64 + 8);
      xa3 = *(const float4*)(xsrc + (ks + 1) * 64 + 12);
      STAGE_W(cur ^ 1, ks + 1);
    }
    const char* xb0 = (const char*)Xlds[cur];
    const char* wb0 = (const char*)Wlds[cur];
    __builtin_amdgcn_s_setprio(1);
#pragma unroll
    for (int k16 = 0; k16 < 4; ++k16) {
      short8 a = *(const short8*)(xb0 + am * 128 + ((k16 * 32 + h * 16) ^ asw));
#pragma unroll
      for (int j = 0; j < 3; ++j) {
        int nrow = (ng * 3 + j) * 32 + n32;
        short8 b = *(const short8*)(wb0 + nrow * 128 +
                                    ((k16 * 32 + h * 16) ^ ((nrow & 7) << 4)));
        acc[j] = MFMA32(a, b, acc[j]);
      }
    }
    __builtin_amdgcn_s_setprio(0);
    cur ^= 1;
  }
#undef STAGE_W
#undef WRITE_X

  // epilogue: C layout col=lane&31, row=(r&3)+8*(r>>2)+4h. Direct stores.
  const int m0e = m0 + mh * 32;
#pragma unroll
  for (int j = 0; j < 3; ++j) {
    int tig = ns * 6 + ng * 3 + j;      // 0..11 global n-tile, wave-uniform
    int gcol = tig * 32 + n32;
    if (tig < 4) {                      // q (scaled)
#pragma unroll
      for (int r = 0; r < 16; ++r) {
        int row = m0e + (r & 3) + 8 * (r >> 2) + 4 * h;
        qout[(size_t)row * 128 + gcol] = f2bf(acc[j][r] * QK_SCALE);
      }
    } else if (tig < 8) {               // k
#pragma unroll
      for (int r = 0; r < 16; ++r) {
        int row = m0e + (r & 3) + 8 * (r >> 2) + 4 * h;
        kout[(size_t)row * 128 + (gcol - 128)] = f2bf(acc[j][r]);
      }
    } else {                            // v -> v^T [B][128][T], 4 consec t
      int d = gcol - 256;
#pragma unroll
      for (int rq = 0; rq < 4; ++rq) {
        int t0 = m0e + rq * 8 + 4 * h;
        ushort4v o4;
#pragma unroll
        for (int i = 0; i < 4; ++i) o4[i] = f2bf(acc[j][rq * 4 + i]);
        *(ushort4v*)&vtout[(size_t)((t0 >> 12) * 128 + d) * 4096 + (t0 & 4095)] = o4;
      }
    }
  }
}

// ---------------- kernel 2: causal flash attention (round-6 verbatim) -------
// Uniform work items: item -> (batch bi, q-tile qt, chunk cc of CHUNK steps).
// 256 thr = 4 waves x 32 q-rows (128-row tile). K/V dbuf, 1 barrier/step.
template <bool SPLIT>
__global__ __launch_bounds__(256, 2) void attn_kernel(const u16* __restrict__ qws,
                                                      const u16* __restrict__ kws,
                                                      const u16* __restrict__ vtws,
                                                      float* __restrict__ out,
                                                      float* __restrict__ opart,
                                                      float* __restrict__ mlpart) {
  __shared__ __align__(16) unsigned char Klds[2][16384];  // [64 kv][128 d] swz
  __shared__ __align__(16) unsigned char Vlds[2][16384];  // [128 d][64 kv] swz

  const int tid = threadIdx.x;
  const int w = tid >> 6;
  const int l = tid & 63;
  const int h = l >> 5, q32 = l & 31;

  int bi, qt, s_lo, s_hi, item;
  if constexpr (SPLIT) {
    item = (int)blockIdx.x;                 // 0..475
    bi = item / PITEMS;
    int r = item - bi * PITEMS;
    int base = 0;
    qt = 0;
    while (true) {                          // <=32 trivial iterations
      int cnt = (qt + 5) / 5;               // ceil((qt+1)/5) chunks for tile qt
      if (r < base + cnt) { break; }
      base += cnt;
      ++qt;
    }
    int cc = r - base;
    int nsteps = 2 * qt + 2;
    s_lo = cc * CHUNK;
    s_hi = (s_lo + CHUNK < nsteps) ? s_lo + CHUNK : nsteps;
  } else {
    item = 0;
    int tb = (int)blockIdx.x;
    bi = tb & 3;
    qt = 31 - (tb >> 2);
    s_lo = 0;
    s_hi = 2 * qt + 2;
  }

  const int q0w = qt * 128 + w * 32;
  const int qg = q0w + q32;
  const int grow = bi * 4096 + qg;          // this lane's global q row
  const int ql = w * 32 + q32;              // row within the 128-row tile

  // Q B-frags resident: col=q32, k = ks*16 + 8h + e
  short8 qf[8];
  const u16* qp = qws + (size_t)grow * 128 + h * 8;
#pragma unroll
  for (int ks = 0; ks < 8; ++ks) qf[ks] = *(const short8*)(qp + ks * 16);

  f32x16 ot[4];
#pragma unroll
  for (int dt = 0; dt < 4; ++dt)
#pragma unroll
    for (int r = 0; r < 16; ++r) ot[dt][r] = 0.f;
  float mreg = NEG_INF, lsum = 0.f;

  const char* kbatch = (const char*)kws + (size_t)bi * 4096 * 256;
  const char* vbatch = (const char*)vtws + (size_t)bi * 128 * 8192;

#define STAGE_KV(buf, kv0)                                                     \
  {                                                                            \
    _Pragma("unroll") for (int c = 0; c < 4; ++c) {                            \
      int L = c * 256 + tid;                                                   \
      int row = L >> 4, chp = L & 15;                                          \
      int gch = chp ^ (row & 7);                                               \
      gload16(kbatch + (size_t)((kv0) + row) * 256 + gch * 16,                 \
              (unsigned char*)Klds[buf] + c * 4096 + w * 1024);                \
    }                                                                          \
    _Pragma("unroll") for (int c = 0; c < 4; ++c) {                            \
      int L = c * 256 + tid;                                                   \
      int row = L >> 3, chp = L & 7;                                           \
      int gch = chp ^ (row & 7);                                               \
      gload16(vbatch + (size_t)row * 8192 + (size_t)(kv0) * 2 + gch * 16,      \
              (unsigned char*)Vlds[buf] + c * 4096 + w * 1024);                \
    }                                                                          \
  }

  STAGE_KV(0, s_lo * 64);
  int cur = 0;

  for (int s = s_lo; s < s_hi; ++s) {
    WAITVM0();                       // buf(cur) landed (own loads)
    __builtin_amdgcn_s_barrier();    // all waves drained + done with buf(cur^1)
    __builtin_amdgcn_sched_barrier(0);
    if (s + 1 < s_hi) STAGE_KV(cur ^ 1, (s + 1) * 64);
    const int kv0 = s * 64;
    const bool active = (kv0 <= q0w + 31);  // wave-uniform

    if (active) {
      // ---- S^T = K · Q^T : rows kv, cols q ----
      f32x16 st0, st1;
#pragma unroll
      for (int r = 0; r < 16; ++r) { st0[r] = 0.f; st1[r] = 0.f; }
      const char* Kb = (const char*)Klds[cur];
      const int sw = (q32 & 7) << 4;
      __builtin_amdgcn_s_setprio(1);
#pragma unroll
      for (int ks = 0; ks < 8; ++ks) {
        int coff = ks * 32 + h * 16;
        short8 a0 = *(const short8*)(Kb + q32 * 256 + (coff ^ sw));
        st0 = MFMA32(a0, qf[ks], st0);
        short8 a1 = *(const short8*)(Kb + (32 + q32) * 256 + (coff ^ sw));
        st1 = MFMA32(a1, qf[ks], st1);
      }
      __builtin_amdgcn_s_setprio(0);

      // ---- causal mask: kv > q -> -inf ----
      if (kv0 + 63 > q0w) {
#pragma unroll
        for (int r = 0; r < 16; ++r) {
          int kvr = kv0 + (r & 3) + 8 * (r >> 2) + 4 * h;
          if (kvr > qg) st0[r] = NEG_INF;
          if (kvr + 32 > qg) st1[r] = NEG_INF;
        }
      }

      // ---- online softmax (exp2 domain), defer-max THR=8 ----
      float tmax = st0[0];
#pragma unroll
      for (int r = 1; r < 16; ++r) tmax = fmaxf(tmax, st0[r]);
#pragma unroll
      for (int r = 0; r < 16; ++r) tmax = fmaxf(tmax, st1[r]);
      tmax = fmaxf(tmax, __shfl_xor(tmax, 32));
      if (!__all(tmax <= mreg + 8.0f)) {
        float mnew = fmaxf(mreg, tmax);
        float alpha = exp2f(mreg - mnew);
        lsum *= alpha;
#pragma unroll
        for (int dt = 0; dt < 4; ++dt)
#pragma unroll
          for (int r = 0; r < 16; ++r) ot[dt][r] *= alpha;
        mreg = mnew;
      }
      float rs = 0.f;
#pragma unroll
      for (int r = 0; r < 16; ++r) { st0[r] = exp2f(st0[r] - mreg); rs += st0[r]; }
#pragma unroll
      for (int r = 0; r < 16; ++r) { st1[r] = exp2f(st1[r] - mreg); rs += st1[r]; }
      rs += __shfl_xor(rs, 32);
      lsum += rs;

      // ---- O^T += V^T · P^T : per kv-16 tile build P B-frag in-register ----
      const char* Vb = (const char*)Vlds[cur];
      __builtin_amdgcn_s_setprio(1);
#pragma unroll
      for (int t = 0; t < 4; ++t) {
        const f32x16& stt = (t < 2) ? st0 : st1;
        const int rb = (t & 1) * 8;
        u32 A0 = cvtpk(stt[rb + 0], stt[rb + 1]);
        u32 C0 = cvtpk(stt[rb + 2], stt[rb + 3]);
        u32 B0 = cvtpk(stt[rb + 4], stt[rb + 5]);
        u32 D0 = cvtpk(stt[rb + 6], stt[rb + 7]);
        u32 Ax = (u32)__shfl_xor((int)A0, 32);
        u32 Bx = (u32)__shfl_xor((int)B0, 32);
        u32 Cx = (u32)__shfl_xor((int)C0, 32);
        u32 Dx = (u32)__shfl_xor((int)D0, 32);
        int4v pbv;
        pbv[0] = (int)(h ? Bx : A0);
        pbv[1] = (int)(h ? Dx : C0);
        pbv[2] = (int)(h ? B0 : Ax);
        pbv[3] = (int)(h ? D0 : Cx);
        short8 pb = __builtin_bit_cast(short8, pbv);
#pragma unroll
        for (int dt = 0; dt < 4; ++dt) {
          int row = dt * 32 + q32;
          short8 va = *(const short8*)(Vb + row * 128 + ((t * 32 + h * 16) ^ sw));
          ot[dt] = MFMA32(va, pb, ot[dt]);
        }
      }
      __builtin_amdgcn_s_setprio(0);
    }
    cur ^= 1;
  }

  if constexpr (!SPLIT) {
    float inv = 1.0f / lsum;
    float* ob = out + (size_t)grow * 128;
#pragma unroll
    for (int dt = 0; dt < 4; ++dt)
#pragma unroll
      for (int rq = 0; rq < 4; ++rq) {
        f32x4 v4;
#pragma unroll
        for (int i = 0; i < 4; ++i) v4[i] = ot[dt][rq * 4 + i] * inv;
        *(f32x4*)(ob + dt * 32 + rq * 8 + 4 * h) = v4;
      }
  } else {
    float* ob = opart + (size_t)item * 16384 + (size_t)ql * 128;
#pragma unroll
    for (int dt = 0; dt < 4; ++dt)
#pragma unroll
      for (int rq = 0; rq < 4; ++rq) {
        f32x4 v4;
#pragma unroll
        for (int i = 0; i < 4; ++i) v4[i] = ot[dt][rq * 4 + i];
        *(f32x4*)(ob + dt * 32 + rq * 8 + 4 * h) = v4;
      }
    if (h == 0) {
      mlpart[item * 128 + ql] = mreg;
      mlpart[NITEMS * 128 + item * 128 + ql] = lsum;
    }
  }
#undef STAGE_KV
}

// ---------------- kernel 3: variable-split combine (round-6 verbatim) -------
__global__ __launch_bounds__(256) void combine_kernel(const float* __restrict__ opart,
                                                      const float* __restrict__ mlpart,
                                                      float* __restrict__ out) {
  int idx = blockIdx.x * 256 + threadIdx.x;  // 16384*128 threads
  int row = idx >> 7, d = idx & 127;
  int bi = row >> 12, lrow = row & 4095;
  int qt = lrow >> 7, ql = lrow & 127;
  int base = 0;
#pragma unroll 1
  for (int j = 0; j < qt; ++j) base += (j + 5) / 5;
  int nspl = (qt + 5) / 5;
  int it0 = bi * PITEMS + base;

  float M = NEG_INF;
#pragma unroll 1
  for (int j = 0; j < nspl; ++j)
    M = fmaxf(M, mlpart[(it0 + j) * 128 + ql]);
  float L = 0.f, O = 0.f;
#pragma unroll 1
  for (int j = 0; j < nspl; ++j) {
    float s = exp2f(mlpart[(it0 + j) * 128 + ql] - M);
    L += mlpart[NITEMS * 128 + (it0 + j) * 128 + ql] * s;
    O += opart[(size_t)(it0 + j) * 16384 + (size_t)ql * 128 + d] * s;
  }
  out[(size_t)row * 128 + d] = O / L;
}

// ---------------------------------------------------------------------------
extern "C" void kernel_launch(void* const* d_in, const int* in_sizes, int n_in,
                              void* d_out, int out_size, void* d_ws, size_t ws_size,
                              hipStream_t stream) {
  (void)in_sizes; (void)n_in; (void)out_size;
  const float* x  = (const float*)d_in[0];
  const float* Wq = (const float*)d_in[1];
  const float* Wk = (const float*)d_in[2];
  const float* Wv = (const float*)d_in[3];
  float* out = (float*)d_out;
  char* ws = (char*)d_ws;
  u16* qws  = (u16*)(ws);
  u16* kws  = (u16*)(ws + (4u << 20));
  u16* vtws = (u16*)(ws + (8u << 20));
  u16* Wb   = (u16*)(ws + (12u << 20));
  float* opart  = (float*)(ws + (13u << 20));   // 476*64KB = 29.75 MiB
  float* mlpart = (float*)(ws + (47u << 20));   // 2*476*128*4B = 476 KiB

  wconv_kernel<<<dim3(192), dim3(256), 0, stream>>>(Wq, Wk, Wv, Wb);
  qkv_proj_kernel<<<dim3(512), dim3(256), 0, stream>>>(x, Wb, qws, kws, vtws);
  if (ws_size >= ((size_t)48 << 20)) {
    attn_kernel<true><<<dim3(NITEMS), dim3(256), 0, stream>>>(qws, kws, vtws, nullptr, opart, mlpart);
    combine_kernel<<<dim3(8192), dim3(256), 0, stream>>>(opart, mlpart, out);
  } else {
    attn_kernel<false><<<dim3(128), dim3(256), 0, stream>>>(qws, kws, vtws, out, nullptr, nullptr);
  }
}